// Round 1
// baseline (418.590 us; speedup 1.0000x reference)
//
#include <hip/hip_runtime.h>
#include <hip/hip_fp16.h>

// GCN 3-layer encoder, aggregate-first form (A_hat commutes with W):
//   per layer: agg = D^-1/2 (A+I) D^-1/2 X   (gather in dim 64, fp16 staged)
//              out = act(agg @ W + b) [* dis, packed fp16 for next gather]
// CSR build: two-level bucketed (bucket = 256 dst nodes) so every random
// scatter lands in a block-owned LDS-cursored window -> no global atomics, no
// cross-XCD partial-line write amplification (r8: fill_kernel wrote 69 MB for
// 4 MB payload).
// LESSON (r3/r4): never take addresses of register data; cap tiled-GEMM K
// unroll at 2 (full unroll -> 256 VGPR + scratch spill).
// LESSON (r5/r7/r8): gather is latency/fetch-bound; fp16 staging halves bytes.
// r9 (this round): gemm64 is LDS-b128-throughput-bound (~12cyc/instr), and
// agg round-trips 51 MB/layer through HBM purely as a gather->GEMM interface.
// Layers 1/2 now use gcn_fused64: per-node register GEMM (W slice in 64 VGPR,
// zero LDS) fused into the gather epilogue. L3 (128 cols) keeps the split path.
// NOTE: per-XCD L2 reuse for the gather is capped at deg/8 XCDs = 1.25 --
// dim-sliced multi-pass blocking computes to IDENTICAL fill traffic; don't try.

#define NBMAX 512   // max buckets (n <= 131072)
#define EPB   8192  // edges per binning block

// ---------------- bucketed CSR build ----------------

// A: per-block bucket histogram -> hist[block][bucket]
__global__ __launch_bounds__(256) void bin_hist(const int* __restrict__ dst,
                                                int* __restrict__ hist, int E, int NB) {
  __shared__ int cnt[NBMAX];
  for (int i = threadIdx.x; i < NB; i += 256) cnt[i] = 0;
  __syncthreads();
  int base = blockIdx.x * EPB;
  for (int it = 0; it < EPB; it += 256) {
    int e = base + it + threadIdx.x;
    if (e < E) atomicAdd(&cnt[dst[e] >> 8], 1);
  }
  __syncthreads();
  for (int i = threadIdx.x; i < NB; i += 256) hist[(size_t)blockIdx.x * NB + i] = cnt[i];
}

// B1: per bucket, exclusive scan over blocks (in place); totals out.
// Requires nblk <= 256 (E=1e6, EPB=8192 -> 123).
__global__ __launch_bounds__(256) void bucket_prefix(int* __restrict__ hist,
                                                     int* __restrict__ bucket_tot,
                                                     int nblk, int NB) {
  __shared__ int tmp[256];
  int b = blockIdx.x;
  int t = threadIdx.x;
  int v = (t < nblk) ? hist[(size_t)t * NB + b] : 0;
  tmp[t] = v;
  __syncthreads();
  for (int off = 1; off < 256; off <<= 1) {
    int a = (t >= off) ? tmp[t - off] : 0;
    __syncthreads();
    tmp[t] += a;
    __syncthreads();
  }
  if (t < nblk) hist[(size_t)t * NB + b] = tmp[t] - v;  // exclusive over blocks
  if (t == 255) bucket_tot[b] = tmp[255];
}

// B2: exclusive scan of bucket totals -> bucket_off[0..NB], bucket_off[NB]=E.
__global__ __launch_bounds__(512) void bucket_scan(const int* __restrict__ bucket_tot,
                                                   int* __restrict__ bucket_off, int NB, int E) {
  __shared__ int tmp[NBMAX];
  int t = threadIdx.x;
  int v = (t < NB) ? bucket_tot[t] : 0;
  tmp[t] = v;
  __syncthreads();
  for (int off = 1; off < 512; off <<= 1) {
    int a = (t >= off) ? tmp[t - off] : 0;
    __syncthreads();
    tmp[t] += a;
    __syncthreads();
  }
  if (t < NB) bucket_off[t] = tmp[t] - v;
  if (t == 0) bucket_off[NB] = E;
}

// C: scatter (src,dst) pairs into bucket-contiguous regions, LDS cursors.
__global__ __launch_bounds__(256) void bin_scatter(const int* __restrict__ src,
                                                   const int* __restrict__ dst,
                                                   const int* __restrict__ chunk_excl,
                                                   const int* __restrict__ bucket_off,
                                                   int2* __restrict__ pairs, int E, int NB) {
  __shared__ int cur[NBMAX];
  for (int i = threadIdx.x; i < NB; i += 256)
    cur[i] = bucket_off[i] + chunk_excl[(size_t)blockIdx.x * NB + i];
  __syncthreads();
  int base = blockIdx.x * EPB;
  for (int it = 0; it < EPB; it += 256) {
    int e = base + it + threadIdx.x;
    if (e < E) {
      int d = dst[e];
      int pos = atomicAdd(&cur[d >> 8], 1);
      pairs[pos] = make_int2(src[e], d);
    }
  }
}

// D: per bucket: node histogram -> row_ptr + dis; CSR fill with LDS cursors.
__global__ __launch_bounds__(256) void bucket_fill(const int2* __restrict__ pairs,
                                                   const int* __restrict__ bucket_off,
                                                   int* __restrict__ row_ptr,
                                                   int* __restrict__ csr_src,
                                                   float* __restrict__ dis, int n, int NB) {
  __shared__ int cnt[256];
  __shared__ int tmp[256];
  __shared__ int cur[256];
  int b = blockIdx.x;
  int t = threadIdx.x;
  int node_base = b << 8;
  int ebeg = bucket_off[b];
  int eend = bucket_off[b + 1];
  cnt[t] = 0;
  __syncthreads();
  for (int e = ebeg + t; e < eend; e += 256) {
    atomicAdd(&cnt[pairs[e].y - node_base], 1);
  }
  __syncthreads();
  int v = cnt[t];
  tmp[t] = v;
  __syncthreads();
  for (int off = 1; off < 256; off <<= 1) {
    int a = (t >= off) ? tmp[t - off] : 0;
    __syncthreads();
    tmp[t] += a;
    __syncthreads();
  }
  int excl = tmp[t] - v;
  int node = node_base + t;
  if (node < n) {
    row_ptr[node] = ebeg + excl;
    dis[node] = rsqrtf((float)v + 1.0f);  // +1 = self-loop
  }
  cur[t] = ebeg + excl;
  if (b == NB - 1 && t == 0) row_ptr[n] = eend;
  __syncthreads();
  for (int e = ebeg + t; e < eend; e += 256) {
    int2 p = pairs[e];
    int pos = atomicAdd(&cur[p.y - node_base], 1);
    csr_src[pos] = p.x;
  }
}

// ---------------- fp16 pack/unpack (register-only bit ops) ----------------

__device__ __forceinline__ unsigned int packh(float a, float b) {
  unsigned int lo = (unsigned int)__half_as_ushort(__float2half_rn(a));
  unsigned int hi = (unsigned int)__half_as_ushort(__float2half_rn(b));
  return lo | (hi << 16);
}

__device__ __forceinline__ void unpack_add(float& x0, float& x1, unsigned int u) {
  x0 += __half2float(__ushort_as_half((unsigned short)(u & 0xffffu)));
  x1 += __half2float(__ushort_as_half((unsigned short)(u >> 16)));
}

// ---------------- prescale: xs = fp16(x * dis[row])  (n x 64) ----------------

__global__ void prescale_h(const float* __restrict__ x, const float* __restrict__ dis,
                           unsigned short* __restrict__ xs, int n) {
  int i = blockIdx.x * blockDim.x + threadIdx.x;  // over n*8 16B-chunks
  if (i >= n * 8) return;
  int row = i >> 3;
  float s = dis[row];
  const float4* p = (const float4*)(x + (size_t)i * 8);
  float4 f0 = p[0];
  float4 f1 = p[1];
  uint4 u;
  u.x = packh(f0.x * s, f0.y * s);
  u.y = packh(f0.z * s, f0.w * s);
  u.z = packh(f1.x * s, f1.y * s);
  u.w = packh(f1.z * s, f1.w * s);
  *(uint4*)(xs + (size_t)i * 8) = u;
}

// ------- gather (dim 64, fp16 in): agg[d] = dis[d]*(in[d] + sum in[s]) -------
// Wave per node. Lane = eg*8 + fs: edge slot eg in [0,8), slice fs in [0,8)
// covering halves [8*fs, 8*fs+8). Two edge groups per iteration (16 edges).
// (kept for layer 3, which needs a 128-col fp32 GEMM afterwards)

__global__ __launch_bounds__(256) void gather64h(const int* __restrict__ row_ptr,
                                                 const int* __restrict__ csr_src,
                                                 const unsigned short* __restrict__ in,
                                                 const float* __restrict__ dis,
                                                 float* __restrict__ agg, int n) {
  int node = blockIdx.x * (blockDim.x >> 6) + (threadIdx.x >> 6);
  int t = threadIdx.x & 63;
  int eg = t >> 3;  // edge slot 0..7
  int fs = t & 7;   // 16B slice 0..7
  if (node >= n) return;  // wave-uniform

  int beg = row_ptr[node];
  int end = row_ptr[node + 1];

  float a0 = 0.f, a1 = 0.f, a2 = 0.f, a3 = 0.f;
  float a4 = 0.f, a5 = 0.f, a6 = 0.f, a7 = 0.f;

  if (eg == 0) {  // self-loop
    uint4 r = *(const uint4*)(in + (size_t)node * 64 + fs * 8);
    unpack_add(a0, a1, r.x); unpack_add(a2, a3, r.y);
    unpack_add(a4, a5, r.z); unpack_add(a6, a7, r.w);
  }

  for (int k = beg; k < end; k += 16) {
    int e0 = k + eg;
    int e1 = k + 8 + eg;
    if (e0 < end) {
      int s = csr_src[e0];
      uint4 r = *(const uint4*)(in + (size_t)s * 64 + fs * 8);
      unpack_add(a0, a1, r.x); unpack_add(a2, a3, r.y);
      unpack_add(a4, a5, r.z); unpack_add(a6, a7, r.w);
    }
    if (e1 < end) {
      int s = csr_src[e1];
      uint4 r = *(const uint4*)(in + (size_t)s * 64 + fs * 8);
      unpack_add(a0, a1, r.x); unpack_add(a2, a3, r.y);
      unpack_add(a4, a5, r.z); unpack_add(a6, a7, r.w);
    }
  }

  // butterfly over the 8 edge slots (lane strides 8, 16, 32)
#pragma unroll
  for (int m = 8; m <= 32; m <<= 1) {
    a0 += __shfl_xor(a0, m); a1 += __shfl_xor(a1, m);
    a2 += __shfl_xor(a2, m); a3 += __shfl_xor(a3, m);
    a4 += __shfl_xor(a4, m); a5 += __shfl_xor(a5, m);
    a6 += __shfl_xor(a6, m); a7 += __shfl_xor(a7, m);
  }

  if (eg == 0) {
    float sc = dis[node];
    float4 lo = make_float4(a0 * sc, a1 * sc, a2 * sc, a3 * sc);
    float4 hi = make_float4(a4 * sc, a5 * sc, a6 * sc, a7 * sc);
    *(float4*)&agg[(size_t)node * 64 + fs * 8] = lo;
    *(float4*)&agg[(size_t)node * 64 + fs * 8 + 4] = hi;
  }
}

// ------- fused gather + per-node register GEMM (layers 1/2, 64x64 W) -------
// out[node][c] = pack_fp16( relu( (dis[d]*(self+sum src)) @ W + b ) * dis[d] )
// Wave per node (grid-stride). Lane (eg,fs) keeps W[8fs+j][8eg+i] in 64 VGPRs
// (loaded once per wave); after the eg-butterfly every lane holds the full
// agg k-slice [8fs,8fs+8), so the 64x64 matvec is 64 register FMAs/lane with
// a 3-level fs-butterfly to finish. Zero LDS; VALU overlaps gather latency.

__global__ __launch_bounds__(256, 4) void gcn_fused64(
    const int* __restrict__ row_ptr, const int* __restrict__ csr_src,
    const unsigned short* __restrict__ in, const float* __restrict__ dis,
    const float* __restrict__ W, const float* __restrict__ Bv,
    unsigned short* __restrict__ out, int n) {
  int t = threadIdx.x & 63;
  int eg = t >> 3;  // output c-slice [8*eg, 8*eg+8)
  int fs = t & 7;   // k-slice [8*fs, 8*fs+8)

  // W slice into registers: w[j][i] = W[(8*fs + j)][8*eg + i]
  float w[8][8];
  {
    const float* wp = W + (size_t)(fs * 8) * 64 + eg * 8;
#pragma unroll
    for (int j = 0; j < 8; ++j) {
      float4 lo = *(const float4*)(wp + (size_t)j * 64);
      float4 hi = *(const float4*)(wp + (size_t)j * 64 + 4);
      w[j][0] = lo.x; w[j][1] = lo.y; w[j][2] = lo.z; w[j][3] = lo.w;
      w[j][4] = hi.x; w[j][5] = hi.y; w[j][6] = hi.z; w[j][7] = hi.w;
    }
  }
  float4 bl = *(const float4*)(Bv + eg * 8);
  float4 bh = *(const float4*)(Bv + eg * 8 + 4);

  int wid = blockIdx.x * 4 + (threadIdx.x >> 6);
  int nw = gridDim.x * 4;

  for (int node = wid; node < n; node += nw) {
    int beg = row_ptr[node];
    int end = row_ptr[node + 1];
    float s = dis[node];

    float a[8];
#pragma unroll
    for (int i = 0; i < 8; ++i) a[i] = 0.f;

    if (eg == 0) {  // self-loop
      uint4 r = *(const uint4*)(in + (size_t)node * 64 + fs * 8);
      unpack_add(a[0], a[1], r.x); unpack_add(a[2], a[3], r.y);
      unpack_add(a[4], a[5], r.z); unpack_add(a[6], a[7], r.w);
    }

    for (int k = beg; k < end; k += 16) {
      int e0 = k + eg;
      int e1 = k + 8 + eg;
      if (e0 < end) {
        int ssrc = csr_src[e0];
        uint4 r = *(const uint4*)(in + (size_t)ssrc * 64 + fs * 8);
        unpack_add(a[0], a[1], r.x); unpack_add(a[2], a[3], r.y);
        unpack_add(a[4], a[5], r.z); unpack_add(a[6], a[7], r.w);
      }
      if (e1 < end) {
        int ssrc = csr_src[e1];
        uint4 r = *(const uint4*)(in + (size_t)ssrc * 64 + fs * 8);
        unpack_add(a[0], a[1], r.x); unpack_add(a[2], a[3], r.y);
        unpack_add(a[4], a[5], r.z); unpack_add(a[6], a[7], r.w);
      }
    }

    // butterfly over the 8 edge slots -> every lane has full k-slice sums
#pragma unroll
    for (int m = 8; m <= 32; m <<= 1) {
#pragma unroll
      for (int i = 0; i < 8; ++i) a[i] += __shfl_xor(a[i], m);
    }
#pragma unroll
    for (int i = 0; i < 8; ++i) a[i] *= s;  // agg = dis[d] * sum

    // 8x8 register matvec: o[i] partial over this lane's k-slice
    float o[8];
#pragma unroll
    for (int i = 0; i < 8; ++i) o[i] = 0.f;
#pragma unroll
    for (int j = 0; j < 8; ++j) {
#pragma unroll
      for (int i = 0; i < 8; ++i) o[i] = fmaf(a[j], w[j][i], o[i]);
    }

    // reduce partials over fs (lane strides 1, 2, 4) -> full dot over k=64
#pragma unroll
    for (int m = 1; m <= 4; m <<= 1) {
#pragma unroll
      for (int i = 0; i < 8; ++i) o[i] += __shfl_xor(o[i], m);
    }

    if (fs == 0) {  // lanes 0,8,...,56: write c-slices, 128B/wave contiguous
      o[0] += bl.x; o[1] += bl.y; o[2] += bl.z; o[3] += bl.w;
      o[4] += bh.x; o[5] += bh.y; o[6] += bh.z; o[7] += bh.w;
#pragma unroll
      for (int i = 0; i < 8; ++i) o[i] = fmaxf(o[i], 0.f) * s;  // relu, pre-scale
      uint4 u;
      u.x = packh(o[0], o[1]); u.y = packh(o[2], o[3]);
      u.z = packh(o[4], o[5]); u.w = packh(o[6], o[7]);
      *(uint4*)(out + (size_t)node * 64 + eg * 8) = u;
    }
  }
}

// ---------------- tiled GEMM (64-row x 64-col slab) ----------------
// out[r, cb+c] = act( sum_k X[r,k] W[k, cb+c] + b[cb+c] ) [* dis[r]]
// X stride 64 fp32, W stride ldw. Output: fp32 (yF) or packed fp16 (yH).
// (kept for layer 3 only: 128 output cols, fp32 out)

__device__ __forceinline__ void fma4(float4& a, float s, const float4 w) {
  a.x = fmaf(s, w.x, a.x);
  a.y = fmaf(s, w.y, a.y);
  a.z = fmaf(s, w.z, a.z);
  a.w = fmaf(s, w.w, a.w);
}

template <bool RELU, bool SCALE, bool OUTH>
__global__ __launch_bounds__(256, 4) void gemm64(const float* __restrict__ X,
                                                 const float* __restrict__ W,
                                                 const float* __restrict__ B,
                                                 const float* __restrict__ dis,
                                                 float* __restrict__ yF,
                                                 unsigned short* __restrict__ yH,
                                                 int n, int ldw) {
  __shared__ float Xs[64 * 68];
  __shared__ float Ws[64 * 64];
  int tid = threadIdx.x;
  int rb = blockIdx.x * 64;
  int cb = blockIdx.y * 64;

  for (int i = tid; i < 1024; i += 256) {
    int k = i >> 4, cq = (i & 15) << 2;
    *(float4*)&Ws[k * 64 + cq] = *(const float4*)&W[(size_t)k * ldw + cb + cq];
  }
  for (int i = tid; i < 1024; i += 256) {
    int r = i >> 4, kq = (i & 15) << 2;
    int gr = rb + r;
    float4 v = make_float4(0.f, 0.f, 0.f, 0.f);
    if (gr < n) v = *(const float4*)&X[(size_t)gr * 64 + kq];
    *(float4*)&Xs[r * 68 + kq] = v;
  }
  __syncthreads();

  int r0 = (tid >> 4) << 2;
  int c0 = (tid & 15) << 2;

  float4 a0 = make_float4(0.f, 0.f, 0.f, 0.f);
  float4 a1 = a0, a2 = a0, a3 = a0;

#pragma unroll 2
  for (int kc = 0; kc < 64; kc += 4) {
    float4 x0 = *(const float4*)&Xs[(r0 + 0) * 68 + kc];
    float4 x1 = *(const float4*)&Xs[(r0 + 1) * 68 + kc];
    float4 x2 = *(const float4*)&Xs[(r0 + 2) * 68 + kc];
    float4 x3 = *(const float4*)&Xs[(r0 + 3) * 68 + kc];
    float4 w0 = *(const float4*)&Ws[(kc + 0) * 64 + c0];
    float4 w1 = *(const float4*)&Ws[(kc + 1) * 64 + c0];
    float4 w2 = *(const float4*)&Ws[(kc + 2) * 64 + c0];
    float4 w3 = *(const float4*)&Ws[(kc + 3) * 64 + c0];
    fma4(a0, x0.x, w0); fma4(a0, x0.y, w1); fma4(a0, x0.z, w2); fma4(a0, x0.w, w3);
    fma4(a1, x1.x, w0); fma4(a1, x1.y, w1); fma4(a1, x1.z, w2); fma4(a1, x1.w, w3);
    fma4(a2, x2.x, w0); fma4(a2, x2.y, w1); fma4(a2, x2.z, w2); fma4(a2, x2.w, w3);
    fma4(a3, x3.x, w0); fma4(a3, x3.y, w1); fma4(a3, x3.z, w2); fma4(a3, x3.w, w3);
  }

  float4 bb = *(const float4*)&B[cb + c0];
  int gr0 = rb + r0;
#pragma unroll
  for (int ri = 0; ri < 4; ++ri) {
    int gr = gr0 + ri;
    if (gr >= n) break;
    float4 v = (ri == 0) ? a0 : (ri == 1) ? a1 : (ri == 2) ? a2 : a3;
    v.x += bb.x; v.y += bb.y; v.z += bb.z; v.w += bb.w;
    if (RELU) {
      v.x = fmaxf(v.x, 0.f); v.y = fmaxf(v.y, 0.f);
      v.z = fmaxf(v.z, 0.f); v.w = fmaxf(v.w, 0.f);
    }
    if (SCALE) {
      float s = dis[gr];
      v.x *= s; v.y *= s; v.z *= s; v.w *= s;
    }
    if (OUTH) {
      uint2 u;
      u.x = packh(v.x, v.y);
      u.y = packh(v.z, v.w);
      *(uint2*)(yH + (size_t)gr * ldw + cb + c0) = u;
    } else {
      *(float4*)&yF[(size_t)gr * ldw + cb + c0] = v;
    }
  }
}

// ---------------- launch ----------------

extern "C" void kernel_launch(void* const* d_in, const int* in_sizes, int n_in,
                              void* d_out, int out_size, void* d_ws, size_t ws_size,
                              hipStream_t stream) {
  const float* x  = (const float*)d_in[0];
  const float* W1 = (const float*)d_in[1];
  const float* b1 = (const float*)d_in[2];
  const float* W2 = (const float*)d_in[3];
  const float* b2 = (const float*)d_in[4];
  const float* W3 = (const float*)d_in[5];
  const float* b3 = (const float*)d_in[6];
  const int*   ei = (const int*)d_in[7];

  const int n = in_sizes[0] / 64;   // 100000
  const int E = in_sizes[7] / 2;    // 1000000
  const int* src = ei;
  const int* dst = ei + E;

  const int NB    = (n + 255) >> 8;         // buckets (256 nodes each): 391
  const int nblkA = (E + EPB - 1) / EPB;    // binning blocks: 123

  // Workspace: dis[n] f32 | bufA[n*64] fp16 | bufB[n*64] fp16 | agg[n*64] f32 |
  //            row_ptr[n+2] | csr_src[E] | pairs[E] int2 | hist | tot | off
  float* dis = (float*)d_ws;
  unsigned short* bufA = (unsigned short*)(dis + n);
  unsigned short* bufB = bufA + (size_t)n * 64;
  float* agg = (float*)(bufB + (size_t)n * 64);
  int* row_ptr = (int*)(agg + (size_t)n * 64);
  int* csr_src = row_ptr + (n + 2);         // +2 keeps pairs 8B-aligned
  int2* pairs  = (int2*)(csr_src + E);
  int* hist       = (int*)(pairs + E);
  int* bucket_tot = hist + (size_t)nblkA * NB;
  int* bucket_off = bucket_tot + NB;
  float* out = (float*)d_out;

  dim3 blk(256);
  int gW = (n + 3) / 4;           // gather: 4 waves (nodes) per block
  int gT = (n + 63) / 64;         // gemm: 64-row tiles
  int gS = (n * 8 + 255) / 256;   // prescale: 16B chunks
  int gF = 6250;                  // fused: 25000 waves, 4 nodes/wave

  // --- bucketed CSR build (+ dis) ---
  bin_hist<<<nblkA, blk, 0, stream>>>(dst, hist, E, NB);
  bucket_prefix<<<NB, blk, 0, stream>>>(hist, bucket_tot, nblkA, NB);
  bucket_scan<<<1, 512, 0, stream>>>(bucket_tot, bucket_off, NB, E);
  bin_scatter<<<nblkA, blk, 0, stream>>>(src, dst, hist, bucket_off, pairs, E, NB);
  bucket_fill<<<NB, blk, 0, stream>>>(pairs, bucket_off, row_ptr, csr_src, dis, n, NB);

  // --- prescale input to fp16 ---
  prescale_h<<<gS, blk, 0, stream>>>(x, dis, bufA, n);

  // --- Layer 1: fused gather + register GEMM (relu, scale, fp16 out) ---
  gcn_fused64<<<gF, blk, 0, stream>>>(row_ptr, csr_src, bufA, dis, W1, b1, bufB, n);

  // --- Layer 2 ---
  gcn_fused64<<<gF, blk, 0, stream>>>(row_ptr, csr_src, bufB, dis, W2, b2, bufA, n);

  // --- Layer 3: gather -> gemm(fp32 out, 128 cols) ---
  gather64h<<<gW, blk, 0, stream>>>(row_ptr, csr_src, bufA, dis, agg, n);
  gemm64<false, false, false><<<dim3(gT, 2), blk, 0, stream>>>(agg, W3, b3, dis, out, nullptr, n, 128);
}

// Round 2
// 273.483 us; speedup vs baseline: 1.5306x; 1.5306x over previous
//
#include <hip/hip_runtime.h>
#include <hip/hip_fp16.h>

// GCN 3-layer encoder, aggregate-first form (A_hat commutes with W):
//   per layer: agg = D^-1/2 (A+I) D^-1/2 X   (gather in dim 64, fp16 staged)
//              out = act(agg @ W + b) [* dis, packed fp16 for next gather]
// CSR build: two-level bucketed (bucket = 256 dst nodes) so every random
// scatter lands in a block-owned LDS-cursored window -> no global atomics.
// LESSON (r3/r4): never take addresses of register data; cap tiled-GEMM K
// unroll at 2 (full unroll -> 256 VGPR + scratch spill).
// LESSON (r5/r7/r8): gather is latency/fetch-bound; fp16 staging halves bytes.
// LESSON (r9, FAILED fusion): per-node register GEMM needs 64 W VGPRs; the
// compiler refuses (VGPR=60 measured -> W reloaded per node) and the extra
// 24 shfl/node doubles DS-pipe time (~45us/layer). Do NOT fuse the matvec
// into the gather wave; keep split gather->gemm.
// r10 (this round): the old gather's 24 ds_bpermute/node butterfly was ~23us
// of DS-pipe per layer. New gather64q: 16 lanes own 4 features each (uint2
// row slice), edges stream with 1 shfl broadcast per 2x4 edges -> ~7 DS/node,
// no reduction. Also EPB 8192->4096 (123 blocks left half the GPU idle).
// NOTE: per-XCD L2 reuse for the gather is capped at deg/8 XCDs = 1.25 --
// dim-sliced multi-pass blocking computes to IDENTICAL fill traffic; don't try.

#define NBMAX 512   // max buckets (n <= 131072)
#define EPB   4096  // edges per binning block (nblkA must stay <= 256)

// ---------------- bucketed CSR build ----------------

// A: per-block bucket histogram -> hist[block][bucket]
__global__ __launch_bounds__(256) void bin_hist(const int* __restrict__ dst,
                                                int* __restrict__ hist, int E, int NB) {
  __shared__ int cnt[NBMAX];
  for (int i = threadIdx.x; i < NB; i += 256) cnt[i] = 0;
  __syncthreads();
  int base = blockIdx.x * EPB;
  for (int it = 0; it < EPB; it += 256) {
    int e = base + it + threadIdx.x;
    if (e < E) atomicAdd(&cnt[dst[e] >> 8], 1);
  }
  __syncthreads();
  for (int i = threadIdx.x; i < NB; i += 256) hist[(size_t)blockIdx.x * NB + i] = cnt[i];
}

// B1: per bucket, exclusive scan over blocks (in place); totals out.
// Requires nblk <= 256 (E=1e6, EPB=4096 -> 245).
__global__ __launch_bounds__(256) void bucket_prefix(int* __restrict__ hist,
                                                     int* __restrict__ bucket_tot,
                                                     int nblk, int NB) {
  __shared__ int tmp[256];
  int b = blockIdx.x;
  int t = threadIdx.x;
  int v = (t < nblk) ? hist[(size_t)t * NB + b] : 0;
  tmp[t] = v;
  __syncthreads();
  for (int off = 1; off < 256; off <<= 1) {
    int a = (t >= off) ? tmp[t - off] : 0;
    __syncthreads();
    tmp[t] += a;
    __syncthreads();
  }
  if (t < nblk) hist[(size_t)t * NB + b] = tmp[t] - v;  // exclusive over blocks
  if (t == 255) bucket_tot[b] = tmp[255];
}

// B2: exclusive scan of bucket totals -> bucket_off[0..NB], bucket_off[NB]=E.
__global__ __launch_bounds__(512) void bucket_scan(const int* __restrict__ bucket_tot,
                                                   int* __restrict__ bucket_off, int NB, int E) {
  __shared__ int tmp[NBMAX];
  int t = threadIdx.x;
  int v = (t < NB) ? bucket_tot[t] : 0;
  tmp[t] = v;
  __syncthreads();
  for (int off = 1; off < 512; off <<= 1) {
    int a = (t >= off) ? tmp[t - off] : 0;
    __syncthreads();
    tmp[t] += a;
    __syncthreads();
  }
  if (t < NB) bucket_off[t] = tmp[t] - v;
  if (t == 0) bucket_off[NB] = E;
}

// C: scatter (src,dst) pairs into bucket-contiguous regions, LDS cursors.
__global__ __launch_bounds__(256) void bin_scatter(const int* __restrict__ src,
                                                   const int* __restrict__ dst,
                                                   const int* __restrict__ chunk_excl,
                                                   const int* __restrict__ bucket_off,
                                                   int2* __restrict__ pairs, int E, int NB) {
  __shared__ int cur[NBMAX];
  for (int i = threadIdx.x; i < NB; i += 256)
    cur[i] = bucket_off[i] + chunk_excl[(size_t)blockIdx.x * NB + i];
  __syncthreads();
  int base = blockIdx.x * EPB;
  for (int it = 0; it < EPB; it += 256) {
    int e = base + it + threadIdx.x;
    if (e < E) {
      int d = dst[e];
      int pos = atomicAdd(&cur[d >> 8], 1);
      pairs[pos] = make_int2(src[e], d);
    }
  }
}

// D: per bucket: node histogram -> row_ptr + dis; CSR fill with LDS cursors.
__global__ __launch_bounds__(256) void bucket_fill(const int2* __restrict__ pairs,
                                                   const int* __restrict__ bucket_off,
                                                   int* __restrict__ row_ptr,
                                                   int* __restrict__ csr_src,
                                                   float* __restrict__ dis, int n, int NB) {
  __shared__ int cnt[256];
  __shared__ int tmp[256];
  __shared__ int cur[256];
  int b = blockIdx.x;
  int t = threadIdx.x;
  int node_base = b << 8;
  int ebeg = bucket_off[b];
  int eend = bucket_off[b + 1];
  cnt[t] = 0;
  __syncthreads();
  for (int e = ebeg + t; e < eend; e += 256) {
    atomicAdd(&cnt[pairs[e].y - node_base], 1);
  }
  __syncthreads();
  int v = cnt[t];
  tmp[t] = v;
  __syncthreads();
  for (int off = 1; off < 256; off <<= 1) {
    int a = (t >= off) ? tmp[t - off] : 0;
    __syncthreads();
    tmp[t] += a;
    __syncthreads();
  }
  int excl = tmp[t] - v;
  int node = node_base + t;
  if (node < n) {
    row_ptr[node] = ebeg + excl;
    dis[node] = rsqrtf((float)v + 1.0f);  // +1 = self-loop
  }
  cur[t] = ebeg + excl;
  if (b == NB - 1 && t == 0) row_ptr[n] = eend;
  __syncthreads();
  for (int e = ebeg + t; e < eend; e += 256) {
    int2 p = pairs[e];
    int pos = atomicAdd(&cur[p.y - node_base], 1);
    csr_src[pos] = p.x;
  }
}

// ---------------- fp16 pack/unpack (register-only bit ops) ----------------

__device__ __forceinline__ unsigned int packh(float a, float b) {
  unsigned int lo = (unsigned int)__half_as_ushort(__float2half_rn(a));
  unsigned int hi = (unsigned int)__half_as_ushort(__float2half_rn(b));
  return lo | (hi << 16);
}

__device__ __forceinline__ void unpack_add(float& x0, float& x1, unsigned int u) {
  x0 += __half2float(__ushort_as_half((unsigned short)(u & 0xffffu)));
  x1 += __half2float(__ushort_as_half((unsigned short)(u >> 16)));
}

// ---------------- prescale: xs = fp16(x * dis[row])  (n x 64) ----------------

__global__ void prescale_h(const float* __restrict__ x, const float* __restrict__ dis,
                           unsigned short* __restrict__ xs, int n) {
  int i = blockIdx.x * blockDim.x + threadIdx.x;  // over n*8 16B-chunks
  if (i >= n * 8) return;
  int row = i >> 3;
  float s = dis[row];
  const float4* p = (const float4*)(x + (size_t)i * 8);
  float4 f0 = p[0];
  float4 f1 = p[1];
  uint4 u;
  u.x = packh(f0.x * s, f0.y * s);
  u.y = packh(f0.z * s, f0.w * s);
  u.z = packh(f1.x * s, f1.y * s);
  u.w = packh(f1.z * s, f1.w * s);
  *(uint4*)(xs + (size_t)i * 8) = u;
}

// ------- gather (dim 64, fp16 in): agg[d] = dis[d]*(in[d] + sum in[s]) -------
// r10 layout: 16 lanes per node (4 nodes/wave), lane owns features
// [4*l15, 4*l15+4) exclusively -> NO reduction butterfly. Edges stream
// serially per node; src index broadcast within the 16-lane group via one
// __shfl (1 DS instr serves 4 nodes x 1 edge). Unroll 2 for MLP.
// Per node: ~7 DS + ~7 VMEM instrs (old: 24 DS + butterfly).

__global__ __launch_bounds__(256) void gather64q(const int* __restrict__ row_ptr,
                                                 const int* __restrict__ csr_src,
                                                 const unsigned short* __restrict__ in,
                                                 const float* __restrict__ dis,
                                                 float* __restrict__ agg, int n) {
  int node = blockIdx.x * 16 + (threadIdx.x >> 4);
  int l15 = threadIdx.x & 15;       // feature slice [4*l15, 4*l15+4)
  int gbase = threadIdx.x & 48;     // group base lane within the wave
  if (node >= n) return;            // group-uniform

  int beg = row_ptr[node];
  int end = row_ptr[node + 1];

  float a0 = 0.f, a1 = 0.f, a2 = 0.f, a3 = 0.f;

  {  // self-loop
    uint2 q = *(const uint2*)(in + (size_t)node * 64 + l15 * 4);
    unpack_add(a0, a1, q.x); unpack_add(a2, a3, q.y);
  }

  for (int kb = beg; kb < end; kb += 16) {
    int idx = (kb + l15 < end) ? csr_src[kb + l15] : 0;  // 16 edges per chunk
    int cnt = end - kb; if (cnt > 16) cnt = 16;          // group-uniform
    int rr = 0;
    for (; rr + 2 <= cnt; rr += 2) {
      int s0 = __shfl(idx, gbase + rr);
      int s1 = __shfl(idx, gbase + rr + 1);
      uint2 q0 = *(const uint2*)(in + (size_t)s0 * 64 + l15 * 4);
      uint2 q1 = *(const uint2*)(in + (size_t)s1 * 64 + l15 * 4);
      unpack_add(a0, a1, q0.x); unpack_add(a2, a3, q0.y);
      unpack_add(a0, a1, q1.x); unpack_add(a2, a3, q1.y);
    }
    if (rr < cnt) {
      int s0 = __shfl(idx, gbase + rr);
      uint2 q0 = *(const uint2*)(in + (size_t)s0 * 64 + l15 * 4);
      unpack_add(a0, a1, q0.x); unpack_add(a2, a3, q0.y);
    }
  }

  float sc = dis[node];
  *(float4*)&agg[(size_t)node * 64 + l15 * 4] =
      make_float4(a0 * sc, a1 * sc, a2 * sc, a3 * sc);
}

// ---------------- tiled GEMM (64-row x 64-col slab) ----------------
// out[r, cb+c] = act( sum_k X[r,k] W[k, cb+c] + b[cb+c] ) [* dis[r]]
// X stride 64 fp32, W stride ldw. Output: fp32 (yF) or packed fp16 (yH).

__device__ __forceinline__ void fma4(float4& a, float s, const float4 w) {
  a.x = fmaf(s, w.x, a.x);
  a.y = fmaf(s, w.y, a.y);
  a.z = fmaf(s, w.z, a.z);
  a.w = fmaf(s, w.w, a.w);
}

template <bool RELU, bool SCALE, bool OUTH>
__global__ __launch_bounds__(256, 4) void gemm64(const float* __restrict__ X,
                                                 const float* __restrict__ W,
                                                 const float* __restrict__ B,
                                                 const float* __restrict__ dis,
                                                 float* __restrict__ yF,
                                                 unsigned short* __restrict__ yH,
                                                 int n, int ldw) {
  __shared__ float Xs[64 * 68];
  __shared__ float Ws[64 * 64];
  int tid = threadIdx.x;
  int rb = blockIdx.x * 64;
  int cb = blockIdx.y * 64;

  for (int i = tid; i < 1024; i += 256) {
    int k = i >> 4, cq = (i & 15) << 2;
    *(float4*)&Ws[k * 64 + cq] = *(const float4*)&W[(size_t)k * ldw + cb + cq];
  }
  for (int i = tid; i < 1024; i += 256) {
    int r = i >> 4, kq = (i & 15) << 2;
    int gr = rb + r;
    float4 v = make_float4(0.f, 0.f, 0.f, 0.f);
    if (gr < n) v = *(const float4*)&X[(size_t)gr * 64 + kq];
    *(float4*)&Xs[r * 68 + kq] = v;
  }
  __syncthreads();

  int r0 = (tid >> 4) << 2;
  int c0 = (tid & 15) << 2;

  float4 a0 = make_float4(0.f, 0.f, 0.f, 0.f);
  float4 a1 = a0, a2 = a0, a3 = a0;

#pragma unroll 2
  for (int kc = 0; kc < 64; kc += 4) {
    float4 x0 = *(const float4*)&Xs[(r0 + 0) * 68 + kc];
    float4 x1 = *(const float4*)&Xs[(r0 + 1) * 68 + kc];
    float4 x2 = *(const float4*)&Xs[(r0 + 2) * 68 + kc];
    float4 x3 = *(const float4*)&Xs[(r0 + 3) * 68 + kc];
    float4 w0 = *(const float4*)&Ws[(kc + 0) * 64 + c0];
    float4 w1 = *(const float4*)&Ws[(kc + 1) * 64 + c0];
    float4 w2 = *(const float4*)&Ws[(kc + 2) * 64 + c0];
    float4 w3 = *(const float4*)&Ws[(kc + 3) * 64 + c0];
    fma4(a0, x0.x, w0); fma4(a0, x0.y, w1); fma4(a0, x0.z, w2); fma4(a0, x0.w, w3);
    fma4(a1, x1.x, w0); fma4(a1, x1.y, w1); fma4(a1, x1.z, w2); fma4(a1, x1.w, w3);
    fma4(a2, x2.x, w0); fma4(a2, x2.y, w1); fma4(a2, x2.z, w2); fma4(a2, x2.w, w3);
    fma4(a3, x3.x, w0); fma4(a3, x3.y, w1); fma4(a3, x3.z, w2); fma4(a3, x3.w, w3);
  }

  float4 bb = *(const float4*)&B[cb + c0];
  int gr0 = rb + r0;
#pragma unroll
  for (int ri = 0; ri < 4; ++ri) {
    int gr = gr0 + ri;
    if (gr >= n) break;
    float4 v = (ri == 0) ? a0 : (ri == 1) ? a1 : (ri == 2) ? a2 : a3;
    v.x += bb.x; v.y += bb.y; v.z += bb.z; v.w += bb.w;
    if (RELU) {
      v.x = fmaxf(v.x, 0.f); v.y = fmaxf(v.y, 0.f);
      v.z = fmaxf(v.z, 0.f); v.w = fmaxf(v.w, 0.f);
    }
    if (SCALE) {
      float s = dis[gr];
      v.x *= s; v.y *= s; v.z *= s; v.w *= s;
    }
    if (OUTH) {
      uint2 u;
      u.x = packh(v.x, v.y);
      u.y = packh(v.z, v.w);
      *(uint2*)(yH + (size_t)gr * ldw + cb + c0) = u;
    } else {
      *(float4*)&yF[(size_t)gr * ldw + cb + c0] = v;
    }
  }
}

// ---------------- launch ----------------

extern "C" void kernel_launch(void* const* d_in, const int* in_sizes, int n_in,
                              void* d_out, int out_size, void* d_ws, size_t ws_size,
                              hipStream_t stream) {
  const float* x  = (const float*)d_in[0];
  const float* W1 = (const float*)d_in[1];
  const float* b1 = (const float*)d_in[2];
  const float* W2 = (const float*)d_in[3];
  const float* b2 = (const float*)d_in[4];
  const float* W3 = (const float*)d_in[5];
  const float* b3 = (const float*)d_in[6];
  const int*   ei = (const int*)d_in[7];

  const int n = in_sizes[0] / 64;   // 100000
  const int E = in_sizes[7] / 2;    // 1000000
  const int* src = ei;
  const int* dst = ei + E;

  const int NB    = (n + 255) >> 8;         // buckets (256 nodes each): 391
  const int nblkA = (E + EPB - 1) / EPB;    // binning blocks: 245

  // Workspace: dis[n] f32 | bufIn[n*64] fp16 | agg[n*64] f32 | row_ptr[n+2] |
  //            csr_src[E] | pairs[E] int2 | hist[nblkA*NB] | tot[NB] | off[NB+1]
  float* dis = (float*)d_ws;
  unsigned short* bufIn = (unsigned short*)(dis + n);
  float* agg = (float*)(bufIn + (size_t)n * 64);
  int* row_ptr = (int*)(agg + (size_t)n * 64);
  int* csr_src = row_ptr + (n + 2);         // +2 keeps pairs 8B-aligned
  int2* pairs  = (int2*)(csr_src + E);
  int* hist       = (int*)(pairs + E);
  int* bucket_tot = hist + (size_t)nblkA * NB;
  int* bucket_off = bucket_tot + NB;
  float* out = (float*)d_out;

  dim3 blk(256);
  int gW = (n + 15) / 16;         // gather: 16 nodes (4 waves x 4 groups) / block
  int gT = (n + 63) / 64;         // gemm: 64-row tiles
  int gS = (n * 8 + 255) / 256;   // prescale: 16B chunks

  // --- bucketed CSR build (+ dis) ---
  bin_hist<<<nblkA, blk, 0, stream>>>(dst, hist, E, NB);
  bucket_prefix<<<NB, blk, 0, stream>>>(hist, bucket_tot, nblkA, NB);
  bucket_scan<<<1, 512, 0, stream>>>(bucket_tot, bucket_off, NB, E);
  bin_scatter<<<nblkA, blk, 0, stream>>>(src, dst, hist, bucket_off, pairs, E, NB);
  bucket_fill<<<NB, blk, 0, stream>>>(pairs, bucket_off, row_ptr, csr_src, dis, n, NB);

  // --- prescale input to fp16 ---
  prescale_h<<<gS, blk, 0, stream>>>(x, dis, bufIn, n);

  // --- Layer 1: gather -> gemm(relu, scale, fp16 out) ---
  gather64q<<<gW, blk, 0, stream>>>(row_ptr, csr_src, bufIn, dis, agg, n);
  gemm64<true, true, true><<<dim3(gT, 1), blk, 0, stream>>>(agg, W1, b1, dis, nullptr, bufIn, n, 64);

  // --- Layer 2 ---
  gather64q<<<gW, blk, 0, stream>>>(row_ptr, csr_src, bufIn, dis, agg, n);
  gemm64<true, true, true><<<dim3(gT, 1), blk, 0, stream>>>(agg, W2, b2, dis, nullptr, bufIn, n, 64);

  // --- Layer 3: gather -> gemm(fp32 out, 128 cols) ---
  gather64q<<<gW, blk, 0, stream>>>(row_ptr, csr_src, bufIn, dis, agg, n);
  gemm64<false, false, false><<<dim3(gT, 2), blk, 0, stream>>>(agg, W3, b3, dis, out, nullptr, n, 128);
}